// Round 8
// baseline (15185.814 us; speedup 1.0000x reference)
//
#include <hip/hip_runtime.h>
#include <hip/hip_bf16.h>
#include <stdint.h>

typedef unsigned int u32;
typedef unsigned long long u64;
typedef __attribute__((ext_vector_type(8))) short short8;
typedef __attribute__((ext_vector_type(4))) float floatx4;

#define T_STEPS 4096
#define BATCH   15
#define N_IN    512
#define N_H     1024
#define G_LAUNCH 64          // launched scan WGs; 8 elected (one XCD) participate
#define THREADS 512          // 8 waves x 16 cols (R7 lesson: keep 2 waves/SIMD overlap)
#define HTAG_WORDS (15*512)  // tagged words per parity buffer (15 batches x 512 pairs)
#define LDS_ROW 516          // u32 per h row: 512 + 4 pad

// ---------- ws layout (bytes) ----------
#define OFF_XP    0
#define OFF_WIHB  (134217728)
#define OFF_HTAG  (134217728 + 1048576)
#define OFF_CLAIM (134217728 + 1048576 + 2*HTAG_WORDS*8)   // u32[16]: 8 counters + winner

__device__ inline u32 f2bf1(float f) {            // fp32 -> bf16 (RNE), as u32
    u32 u = __builtin_bit_cast(u32, f);
    return (u + 0x7FFFu + ((u >> 16) & 1u)) >> 16;
}
__device__ inline float bf2f(u32 us) {            // bf16 (low 16) -> fp32
    return __builtin_bit_cast(float, us << 16);
}
__device__ inline float tanh_fast(float x) {
    float e = __expf(2.0f * x);                   // inf-safe at both ends
    return 1.0f - 2.0f / (e + 1.0f);
}
// Agent-scope load: bypasses L1; served at the shared coherence point.
__device__ inline u64 mb_load(const u64* p) {
    return __hip_atomic_load(p, __ATOMIC_RELAXED, __HIP_MEMORY_SCOPE_AGENT);
}
// Publish store: plain/workgroup scope — tag+data in ONE u64 (atomic word).
__device__ inline void pub_store64(u64* p, u64 v) {
    __hip_atomic_store(p, v, __ATOMIC_RELAXED, __HIP_MEMORY_SCOPE_WORKGROUP);
}
// Release fence: forces this wave's publish stores out of the CU write path
// (R0 without it: ~34 lazy-visibility poll rounds/step; R4 with it: ~1-2).
__device__ inline void release_fence() {
    asm volatile("s_waitcnt vmcnt(0)" ::: "memory");
}

// ---------------- kernel 0: convert W_ih to bf16 (+ zero claim & BOTH tag buffers) ----------------
__global__ void k_cvt_wih(const float* __restrict__ W_ih, u32* __restrict__ wihb,
                          u32* __restrict__ claim, u64* __restrict__ htag) {
    int row = blockIdx.x;
    int tid = threadIdx.x;
    if (row == 0 && tid < 16) claim[tid] = 0;
    // zero both parity tag buffers (60 rows x 256 u64 = 15360 = 2*HTAG_WORDS):
    // kills cross-launch stale-tag hazard; agent stores land at coherence point.
    if (row >= 3 && row < 63)
        __hip_atomic_exchange(htag + (size_t)(row - 3) * 256 + tid, 0ull,
                              __ATOMIC_RELAXED, __HIP_MEMORY_SCOPE_AGENT);
    const float* p = W_ih + (size_t)row * N_IN + tid * 2;
    u32 packed = f2bf1(p[0]) | (f2bf1(p[1]) << 16);
    wihb[row * (N_IN / 2) + tid] = packed;
}

// ---------------- kernel 1: x_proj GEMM ----------------
// xp[((t*64 + cw)*64 + lane)] = bf16x4 (rows quad*4+i, col cw*16+(l&15))
__global__ void __launch_bounds__(256) k_xproj(
        const float* __restrict__ x, const u32* __restrict__ wihb,
        const float* __restrict__ b_ih, const float* __restrict__ b_hh,
        u64* __restrict__ xp) {
    const int t     = blockIdx.x;
    const int slice = blockIdx.y;
    const int tid   = threadIdx.x;
    const int wave  = tid >> 6;
    const int l     = tid & 63;
    const int row   = l & 15;       // batch
    const int quad  = l >> 4;
    const int colbase = slice * 256 + wave * 64;

    floatx4 acc[4] = {{0,0,0,0},{0,0,0,0},{0,0,0,0},{0,0,0,0}};
    const float* xrow = x + ((size_t)row * T_STEPS + t) * N_IN;

    #pragma unroll
    for (int kk = 0; kk < 16; ++kk) {
        short8 a;
        if (row < 15) {
            const float* pa = xrow + kk * 32 + quad * 8;
            float4 x0 = *(const float4*)(pa);
            float4 x1 = *(const float4*)(pa + 4);
            a[0]=(short)f2bf1(x0.x); a[1]=(short)f2bf1(x0.y); a[2]=(short)f2bf1(x0.z); a[3]=(short)f2bf1(x0.w);
            a[4]=(short)f2bf1(x1.x); a[5]=(short)f2bf1(x1.y); a[6]=(short)f2bf1(x1.z); a[7]=(short)f2bf1(x1.w);
        } else {
            #pragma unroll
            for (int j = 0; j < 8; ++j) a[j] = 0;
        }
        #pragma unroll
        for (int c4 = 0; c4 < 4; ++c4) {
            int col = colbase + c4 * 16 + (l & 15);
            const uint4* pb = (const uint4*)(wihb + (size_t)col * (N_IN/2) + kk * 16 + quad * 4);
            short8 b = __builtin_bit_cast(short8, *pb);
            acc[c4] = __builtin_amdgcn_mfma_f32_16x16x32_bf16(a, b, acc[c4], 0, 0, 0);
        }
    }
    #pragma unroll
    for (int c4 = 0; c4 < 4; ++c4) {
        int col = colbase + c4 * 16 + (l & 15);
        float bias = b_ih[col] + b_hh[col];
        u64 packed = (u64)f2bf1(acc[c4][0] + bias)
                   | ((u64)f2bf1(acc[c4][1] + bias) << 16)
                   | ((u64)f2bf1(acc[c4][2] + bias) << 32)
                   | ((u64)f2bf1(acc[c4][3] + bias) << 48);
        int cw = slice * 16 + wave * 4 + c4;
        xp[((size_t)t * 64 + cw) * 64 + l] = packed;
    }
}

// ---------------- kernel 2: sequential scan (8 elected WGs on ONE XCD) ----------------
// Fused poll+fetch: tagged words mean the FIRST poll round that validates also
// delivers the data — no flag indirection, one coherence round-trip per step.
__global__ void __launch_bounds__(THREADS, 2) k_scan(
        const float* __restrict__ W_hh, const u64* __restrict__ xp,
        u64* __restrict__ htag, u32* __restrict__ claim,
        const float* __restrict__ W_fc, const float* __restrict__ b_fc,
        float* __restrict__ out) {
    __shared__ u32 h_lds[2][16 * LDS_ROW];   // ping-pong h (bf16 pairs), row 15 = zero pad
    __shared__ float red[256];
    __shared__ int s_slot;
    __shared__ int s_dead;

    const int tid  = threadIdx.x;      // 0..511
    const int wave = tid >> 6;
    const int l    = tid & 63;
    const int c    = l & 15;           // col-in-tile == batch row (A role)
    const int quad = l >> 4;

    // ---- XCD election: 8 co-XCD WGs win; others exit ----
    if (tid == 0) {
        u32 xcd;
        asm volatile("s_getreg_b32 %0, hwreg(HW_REG_XCC_ID)" : "=s"(xcd));
        xcd &= 7u;
        u32 slot = __hip_atomic_fetch_add(&claim[xcd], 1u, __ATOMIC_RELAXED,
                                          __HIP_MEMORY_SCOPE_AGENT);
        if (slot == 7u) {
            u32 exp = 0u;
            __hip_atomic_compare_exchange_strong(&claim[8], &exp, xcd + 1u,
                __ATOMIC_RELAXED, __ATOMIC_RELAXED, __HIP_MEMORY_SCOPE_AGENT);
        }
        u32 w = 0; int gg = 0;
        do { w = __hip_atomic_load(&claim[8], __ATOMIC_RELAXED, __HIP_MEMORY_SCOPE_AGENT); }
        while (!w && ++gg < (1 << 22));
        s_slot = (w == xcd + 1u && slot < 8u) ? (int)slot : -1;
        s_dead = 0;
    }
    __syncthreads();
    const int g = s_slot;              // 0..7 for participants
    if (g < 0) return;

    const int col  = g * 128 + wave * 16 + c;
    const int cw   = g * 8 + wave;

    // --- W_hh fragments permanently in registers ---
    short8 wf[32];
    {
        const float* wr = W_hh + (size_t)col * N_H;
        #pragma unroll
        for (int kk = 0; kk < 32; ++kk) {
            const float* p = wr + kk * 32 + quad * 8;
            float4 w0 = *(const float4*)(p);
            float4 w1 = *(const float4*)(p + 4);
            short8 bfr;
            bfr[0]=(short)f2bf1(w0.x); bfr[1]=(short)f2bf1(w0.y); bfr[2]=(short)f2bf1(w0.z); bfr[3]=(short)f2bf1(w0.w);
            bfr[4]=(short)f2bf1(w1.x); bfr[5]=(short)f2bf1(w1.y); bfr[6]=(short)f2bf1(w1.z); bfr[7]=(short)f2bf1(w1.w);
            wf[kk] = bfr;
        }
    }
    for (int i = tid; i < 2 * 16 * LDS_ROW; i += THREADS) ((u32*)h_lds)[i] = 0;
    __syncthreads();

    // ---- step 0: h(1) = tanh(xp(0)); publish tagged parity 1; fence ----
    u64 xpw = xp[((size_t)0 * 64 + cw) * 64 + l];
    u64 xpw_n = xp[((size_t)1 * 64 + cw) * 64 + l];
    float h[4];
    {
        h[0] = tanh_fast(bf2f((u32)(xpw      ) & 0xFFFFu));
        h[1] = tanh_fast(bf2f((u32)(xpw >> 16) & 0xFFFFu));
        h[2] = tanh_fast(bf2f((u32)(xpw >> 32) & 0xFFFFu));
        h[3] = tanh_fast(bf2f((u32)(xpw >> 48) & 0xFFFFu));
        u64* bufw = htag + (size_t)1 * HTAG_WORDS;
        #pragma unroll
        for (int i = 0; i < 4; ++i) {
            int bt = quad * 4 + i;
            float o = __shfl_xor(h[i], 1);
            if (!(c & 1) && bt < 15) {
                u32 data = f2bf1(h[i]) | (f2bf1(o) << 16);
                pub_store64(bufw + bt * 512 + (col >> 1), ((u64)1u << 32) | (u64)data);
            }
        }
        release_fence();
    }

    for (int s = 1; s < T_STEPS; ++s) {
        xpw = xpw_n;
        const u64* buf = htag + (size_t)(s & 1) * HTAG_WORDS;
        u32* lds = &h_lds[s & 1][0];
        const u32 tag = (u32)s;

        // ---- fused poll+fetch: word j for thread tid lands at lds[j][tid]
        // (row j = batch, col tid = pair index; ds_write_b32 conflict-free) ----
        {
            u64 v[15];
            #pragma unroll
            for (int j = 0; j < 15; ++j) v[j] = mb_load(buf + tid + j * 512);
            u32 got = 0;
            int rounds = 0;
            while (true) {
                #pragma unroll
                for (int j = 0; j < 15; ++j) {
                    if (!((got >> j) & 1) && (u32)(v[j] >> 32) == tag) {
                        got |= 1u << j;
                        lds[j * LDS_ROW + tid] = (u32)v[j];
                    }
                }
                if (got == 0x7FFFu) break;
                if (++rounds > (1 << 20)) { s_dead = 1; break; }
                #pragma unroll
                for (int j = 0; j < 15; ++j)
                    if (!((got >> j) & 1)) v[j] = mb_load(buf + tid + j * 512);
            }
        }
        __syncthreads();               // the ONLY barrier per step
        if (s_dead) break;

        // ---- xp prefetch for s+1: after the barrier, never outstanding during
        // a poll loop (R5 lesson); consumed via asm-use before the fence ----
        if (s + 1 < T_STEPS) xpw_n = xp[((size_t)(s + 1) * 64 + cw) * 64 + l];

        // ---- compute: fully-unrolled dual-accumulator MFMA chain ----
        floatx4 acc0, acc1;
        acc0[0] = bf2f((u32)(xpw      ) & 0xFFFFu);
        acc0[1] = bf2f((u32)(xpw >> 16) & 0xFFFFu);
        acc0[2] = bf2f((u32)(xpw >> 32) & 0xFFFFu);
        acc0[3] = bf2f((u32)(xpw >> 48) & 0xFFFFu);
        acc1[0] = 0.f; acc1[1] = 0.f; acc1[2] = 0.f; acc1[3] = 0.f;

        #pragma unroll
        for (int t = 0; t < 16; ++t) {
            uint4 a0 = *(const uint4*)&lds[c * LDS_ROW + (2 * t    ) * 16 + quad * 4];
            uint4 a1 = *(const uint4*)&lds[c * LDS_ROW + (2 * t + 1) * 16 + quad * 4];
            acc0 = __builtin_amdgcn_mfma_f32_16x16x32_bf16(
                       __builtin_bit_cast(short8, a0), wf[2 * t    ], acc0, 0, 0, 0);
            acc1 = __builtin_amdgcn_mfma_f32_16x16x32_bf16(
                       __builtin_bit_cast(short8, a1), wf[2 * t + 1], acc1, 0, 0, 0);
        }

        #pragma unroll
        for (int i = 0; i < 4; ++i) h[i] = tanh_fast(acc0[i] + acc1[i]);

        // force xp prefetch completion HERE (covered by MFMA+tanh), so the
        // fence below waits only for the 4 publish stores
        asm volatile("" :: "v"(xpw_n));

        // ---- publish h(s+1): tagged u64s -> parity (s+1)&1; per-wave fence ----
        u64* bufw = htag + (size_t)((s + 1) & 1) * HTAG_WORDS;
        const u32 tag1 = (u32)(s + 1);
        #pragma unroll
        for (int i = 0; i < 4; ++i) {
            int bt = quad * 4 + i;
            float o = __shfl_xor(h[i], 1);
            if (!(c & 1) && bt < 15) {
                u32 data = f2bf1(h[i]) | (f2bf1(o) << 16);
                pub_store64(bufw + bt * 512 + (col >> 1), ((u64)tag1 << 32) | (u64)data);
            }
        }
        release_fence();
    }

    // ---------------- epilogue: elected WG 0 computes the sigmoid head ----------------
    if (g == 0) {
        if (!s_dead) {
            const u64* fbuf = htag + (size_t)(T_STEPS & 1) * HTAG_WORDS;  // parity 0
            const u32 ftag = (u32)T_STEPS;
            u32* lds = &h_lds[0][0];
            u64 v[15];
            #pragma unroll
            for (int j = 0; j < 15; ++j) v[j] = mb_load(fbuf + tid + j * 512);
            u32 got = 0;
            int rounds = 0;
            while (true) {
                #pragma unroll
                for (int j = 0; j < 15; ++j) {
                    if (!((got >> j) & 1) && (u32)(v[j] >> 32) == ftag) {
                        got |= 1u << j;
                        lds[j * LDS_ROW + tid] = (u32)v[j];
                    }
                }
                if (got == 0x7FFFu) break;
                if (++rounds > (1 << 20)) break;
                #pragma unroll
                for (int j = 0; j < 15; ++j)
                    if (!((got >> j) & 1)) v[j] = mb_load(fbuf + tid + j * 512);
            }
        }
        __syncthreads();
        u32* lds = &h_lds[0][0];
        if (tid < 240) {
            int b = tid >> 4, seg = tid & 15;
            float sum = 0.f;
            for (int j = 0; j < 64; ++j) {
                int k = seg * 64 + j;
                u32 pr = lds[b * LDS_ROW + (k >> 1)];
                float hv = bf2f((pr >> ((k & 1) * 16)) & 0xFFFFu);
                sum += hv * W_fc[k];
            }
            red[tid] = sum;
        }
        __syncthreads();
        if (tid < 15) {
            float z = 0.f;
            #pragma unroll
            for (int j = 0; j < 16; ++j) z += red[tid * 16 + j];
            z += b_fc[0];
            out[tid] = 1.0f / (1.0f + __expf(-z));
        }
    }
}

extern "C" void kernel_launch(void* const* d_in, const int* in_sizes, int n_in,
                              void* d_out, int out_size, void* d_ws, size_t ws_size,
                              hipStream_t stream) {
    const float* x    = (const float*)d_in[0];
    const float* W_ih = (const float*)d_in[1];
    const float* b_ih = (const float*)d_in[2];
    const float* W_hh = (const float*)d_in[3];
    const float* b_hh = (const float*)d_in[4];
    const float* W_fc = (const float*)d_in[5];
    const float* b_fc = (const float*)d_in[6];
    float* out = (float*)d_out;

    char* ws    = (char*)d_ws;
    u64*  xp    = (u64*)(ws + OFF_XP);
    u32*  wihb  = (u32*)(ws + OFF_WIHB);
    u64*  htag  = (u64*)(ws + OFF_HTAG);
    u32*  claim = (u32*)(ws + OFF_CLAIM);

    k_cvt_wih<<<dim3(N_H), dim3(256), 0, stream>>>(W_ih, wihb, claim, htag);
    k_xproj<<<dim3(T_STEPS, 4), dim3(256), 0, stream>>>(x, wihb, b_ih, b_hh, xp);
    k_scan<<<dim3(G_LAUNCH), dim3(THREADS), 0, stream>>>(W_hh, xp, htag, claim, W_fc, b_fc, out);
}

// Round 9
// 12629.318 us; speedup vs baseline: 1.2024x; 1.2024x over previous
//
#include <hip/hip_runtime.h>
#include <hip/hip_bf16.h>
#include <stdint.h>

typedef unsigned int u32;
typedef unsigned long long u64;
typedef __attribute__((ext_vector_type(8))) short short8;
typedef __attribute__((ext_vector_type(4))) float floatx4;

#define T_STEPS 4096
#define BATCH   15
#define N_IN    512
#define N_H     1024
#define G_LAUNCH 64          // launched scan WGs; 8 elected (one XCD) participate
#define THREADS 512          // 8 waves x 16 cols
#define LDS_ROW 516          // u32 per h row: 512 + 4 pad

// ---------- ws layout (bytes) ----------
#define OFF_XP    0
#define OFF_WIHB  (134217728)
#define OFF_HBUF  (134217728 + 1048576)           // u32[2][16][512] = 64 KB (row 15 = zero pad)
#define OFF_FLAGS (134217728 + 1048576 + 65536)   // u64[64] @ 64B spacing = 4 KB (per-wave flags)
#define OFF_CLAIM (134217728 + 1048576 + 65536 + 4096)  // u32[16]: 8 counters + winner

__device__ inline u32 f2bf1(float f) {            // fp32 -> bf16 (RNE), as u32
    u32 u = __builtin_bit_cast(u32, f);
    return (u + 0x7FFFu + ((u >> 16) & 1u)) >> 16;
}
__device__ inline float bf2f(u32 us) {            // bf16 (low 16) -> fp32
    return __builtin_bit_cast(float, us << 16);
}
__device__ inline float tanh_fast(float x) {
    float e = __expf(2.0f * x);                   // inf-safe at both ends
    return 1.0f - 2.0f / (e + 1.0f);
}
// Agent-scope load: bypasses L1, hits the shared same-XCD L2.
__device__ inline u64 mb_load(const u64* p) {
    return __hip_atomic_load(p, __ATOMIC_RELAXED, __HIP_MEMORY_SCOPE_AGENT);
}
// Publish store: plain/workgroup scope — dirty line in the local XCD L2.
__device__ inline void pub_store32(u32* p, u32 v) {
    __hip_atomic_store(p, v, __ATOMIC_RELAXED, __HIP_MEMORY_SCOPE_WORKGROUP);
}
__device__ inline void pub_store64(u64* p, u64 v) {
    __hip_atomic_store(p, v, __ATOMIC_RELAXED, __HIP_MEMORY_SCOPE_WORKGROUP);
}
// Per-wave release fence: waits only THIS wave's publish stores (L2 ack).
__device__ inline void release_fence() {
    asm volatile("s_waitcnt vmcnt(0)" ::: "memory");
}
__device__ inline void lds_fence() {               // order ds_write data -> ds_write flag
    asm volatile("s_waitcnt lgkmcnt(0)" ::: "memory");
}

// ---------------- kernel 0: convert W_ih to packed bf16 (+ init claim/flags/zero-row) ----------------
__global__ void k_cvt_wih(const float* __restrict__ W_ih, u32* __restrict__ wihb,
                          u32* __restrict__ claim, u32* __restrict__ hbuf,
                          u64* __restrict__ fl) {
    int row = blockIdx.x;
    int tid = threadIdx.x;
    if (row == 0 && tid < 16) claim[tid] = 0;
    // 64 per-wave flags: zero via agent-scope atomics (coherence point).
    if (row == 0 && tid >= 16 && tid < 80)
        __hip_atomic_exchange(fl + (size_t)(tid - 16) * 8, 0ull,
                              __ATOMIC_RELAXED, __HIP_MEMORY_SCOPE_AGENT);
    // hbuf batch-row 15 (both parities) must read as zero forever.
    if ((row == 1 || row == 2) && tid < 256) {
        u64* hz = (u64*)(hbuf + ((size_t)(row - 1) * 16 + 15) * 512);
        __hip_atomic_exchange(hz + tid, 0ull,
                              __ATOMIC_RELAXED, __HIP_MEMORY_SCOPE_AGENT);
    }
    const float* p = W_ih + (size_t)row * N_IN + tid * 2;
    u32 packed = f2bf1(p[0]) | (f2bf1(p[1]) << 16);
    wihb[row * (N_IN / 2) + tid] = packed;
}

// ---------------- kernel 1: x_proj GEMM ----------------
// xp[((t*64 + cw)*64 + lane)] = bf16x4 (rows quad*4+i, col cw*16+(l&15))
__global__ void __launch_bounds__(256) k_xproj(
        const float* __restrict__ x, const u32* __restrict__ wihb,
        const float* __restrict__ b_ih, const float* __restrict__ b_hh,
        u64* __restrict__ xp) {
    const int t     = blockIdx.x;
    const int slice = blockIdx.y;
    const int tid   = threadIdx.x;
    const int wave  = tid >> 6;
    const int l     = tid & 63;
    const int row   = l & 15;       // batch
    const int quad  = l >> 4;
    const int colbase = slice * 256 + wave * 64;

    floatx4 acc[4] = {{0,0,0,0},{0,0,0,0},{0,0,0,0},{0,0,0,0}};
    const float* xrow = x + ((size_t)row * T_STEPS + t) * N_IN;

    #pragma unroll
    for (int kk = 0; kk < 16; ++kk) {
        short8 a;
        if (row < 15) {
            const float* pa = xrow + kk * 32 + quad * 8;
            float4 x0 = *(const float4*)(pa);
            float4 x1 = *(const float4*)(pa + 4);
            a[0]=(short)f2bf1(x0.x); a[1]=(short)f2bf1(x0.y); a[2]=(short)f2bf1(x0.z); a[3]=(short)f2bf1(x0.w);
            a[4]=(short)f2bf1(x1.x); a[5]=(short)f2bf1(x1.y); a[6]=(short)f2bf1(x1.z); a[7]=(short)f2bf1(x1.w);
        } else {
            #pragma unroll
            for (int j = 0; j < 8; ++j) a[j] = 0;
        }
        #pragma unroll
        for (int c4 = 0; c4 < 4; ++c4) {
            int col = colbase + c4 * 16 + (l & 15);
            const uint4* pb = (const uint4*)(wihb + (size_t)col * (N_IN/2) + kk * 16 + quad * 4);
            short8 b = __builtin_bit_cast(short8, *pb);
            acc[c4] = __builtin_amdgcn_mfma_f32_16x16x32_bf16(a, b, acc[c4], 0, 0, 0);
        }
    }
    #pragma unroll
    for (int c4 = 0; c4 < 4; ++c4) {
        int col = colbase + c4 * 16 + (l & 15);
        float bias = b_ih[col] + b_hh[col];
        u64 packed = (u64)f2bf1(acc[c4][0] + bias)
                   | ((u64)f2bf1(acc[c4][1] + bias) << 16)
                   | ((u64)f2bf1(acc[c4][2] + bias) << 32)
                   | ((u64)f2bf1(acc[c4][3] + bias) << 48);
        int cw = slice * 16 + wave * 4 + c4;
        xp[((size_t)t * 64 + cw) * 64 + l] = packed;
    }
}

// ---------------- kernel 2: sequential scan (8 elected WGs on ONE XCD) ----------------
// Barrier-free main loop: wave w stages producer-WG w's 128-col slice and raises
// an LDS doorbell; compute waves consume slices as they land. Staging latency
// (fence+visibility+poll+fetch ~1400cy) overlaps compute across waves.
__global__ void __launch_bounds__(THREADS, 2) k_scan(
        const float* __restrict__ W_hh, const u64* __restrict__ xp,
        u32* __restrict__ hbuf, u64* __restrict__ fl, u32* __restrict__ claim,
        const float* __restrict__ W_fc, const float* __restrict__ b_fc,
        float* __restrict__ out) {
    __shared__ u32 h_lds[2][16 * LDS_ROW];   // ping-pong h (bf16 pairs), row 15 = zero pad
    __shared__ u32 sflag[2][8];              // LDS slice doorbells (monotone step tags)
    __shared__ float red[256];
    __shared__ int s_slot;
    __shared__ volatile int s_dead_v;

    const int tid  = threadIdx.x;      // 0..511
    const int wave = tid >> 6;
    const int l    = tid & 63;
    const int c    = l & 15;           // col-in-tile == batch row (A role)
    const int quad = l >> 4;

    // ---- XCD election: 8 co-XCD WGs win; others exit ----
    if (tid == 0) {
        u32 xcd;
        asm volatile("s_getreg_b32 %0, hwreg(HW_REG_XCC_ID)" : "=s"(xcd));
        xcd &= 7u;
        u32 slot = __hip_atomic_fetch_add(&claim[xcd], 1u, __ATOMIC_RELAXED,
                                          __HIP_MEMORY_SCOPE_AGENT);
        if (slot == 7u) {
            u32 exp = 0u;
            __hip_atomic_compare_exchange_strong(&claim[8], &exp, xcd + 1u,
                __ATOMIC_RELAXED, __ATOMIC_RELAXED, __HIP_MEMORY_SCOPE_AGENT);
        }
        u32 w = 0; int gg = 0;
        do { w = __hip_atomic_load(&claim[8], __ATOMIC_RELAXED, __HIP_MEMORY_SCOPE_AGENT); }
        while (!w && ++gg < (1 << 22));
        s_slot = (w == xcd + 1u && slot < 8u) ? (int)slot : -1;
        s_dead_v = 0;
    }
    if (tid < 16) ((u32*)sflag)[tid] = 0;
    __syncthreads();
    const int g = s_slot;              // 0..7 for participants
    if (g < 0) return;

    const int col  = g * 128 + wave * 16 + c;
    const int cw   = g * 8 + wave;
    const int wgf  = g * 8 + wave;     // this wave's global flag index

    // --- W_hh fragments permanently in registers ---
    short8 wf[32];
    {
        const float* wr = W_hh + (size_t)col * N_H;
        #pragma unroll
        for (int kk = 0; kk < 32; ++kk) {
            const float* p = wr + kk * 32 + quad * 8;
            float4 w0 = *(const float4*)(p);
            float4 w1 = *(const float4*)(p + 4);
            short8 bfr;
            bfr[0]=(short)f2bf1(w0.x); bfr[1]=(short)f2bf1(w0.y); bfr[2]=(short)f2bf1(w0.z); bfr[3]=(short)f2bf1(w0.w);
            bfr[4]=(short)f2bf1(w1.x); bfr[5]=(short)f2bf1(w1.y); bfr[6]=(short)f2bf1(w1.z); bfr[7]=(short)f2bf1(w1.w);
            wf[kk] = bfr;
        }
    }
    for (int i = tid; i < 2 * 16 * LDS_ROW; i += THREADS) ((u32*)h_lds)[i] = 0;
    __syncthreads();

    // ---- step 0: h(1) = tanh(xp(0)); publish parity 1; per-wave flag = 1 ----
    u64 xpw = xp[((size_t)0 * 64 + cw) * 64 + l];
    u64 xpw_n = xp[((size_t)1 * 64 + cw) * 64 + l];
    float h[4];
    {
        h[0] = tanh_fast(bf2f((u32)(xpw      ) & 0xFFFFu));
        h[1] = tanh_fast(bf2f((u32)(xpw >> 16) & 0xFFFFu));
        h[2] = tanh_fast(bf2f((u32)(xpw >> 32) & 0xFFFFu));
        h[3] = tanh_fast(bf2f((u32)(xpw >> 48) & 0xFFFFu));
        u32* bufw = hbuf + (size_t)1 * (16 * 512);
        #pragma unroll
        for (int i = 0; i < 4; ++i) {
            int bt = quad * 4 + i;
            float o = __shfl_xor(h[i], 1);
            if (!(c & 1) && bt < 15) {
                u32 data = f2bf1(h[i]) | (f2bf1(o) << 16);
                pub_store32(bufw + bt * 512 + (col >> 1), data);
            }
        }
        release_fence();
        if (l == 0) pub_store64(fl + (size_t)wgf * 8, 1ull);
    }

    for (int s = 1; s < T_STEPS; ++s) {
        xpw = xpw_n;
        const int par = s & 1;
        u32* lds = &h_lds[par][0];
        u32* sf  = &sflag[par][0];

        // ---- STAGE slice `wave` (producer WG = wave): poll its 8 wave-flags ----
        {
            const u64 want = (u64)s;
            int r = 0;
            while (!s_dead_v) {
                u64 f = mb_load(fl + (size_t)(wave * 8 + (l & 7)) * 8);
                if (__all((int)(f >= want))) break;
                if (++r > (1 << 18)) { s_dead_v = 1; break; }
            }
        }
        // fetch 7.5KB slice (15 rows x 32 u64), coalesced, L1-bypassed
        {
            const u64* srcp = (const u64*)(hbuf + (size_t)par * (16 * 512));
            u64 d[8];
            #pragma unroll
            for (int j = 0; j < 8; ++j) {
                int idx = l + j * 64;
                if (idx < 480)
                    d[j] = mb_load(srcp + (size_t)(idx >> 5) * 256 + wave * 32 + (idx & 31));
            }
            #pragma unroll
            for (int j = 0; j < 8; ++j) {
                int idx = l + j * 64;
                if (idx < 480)
                    *(u64*)(lds + (size_t)(idx >> 5) * LDS_ROW + wave * 64 + (idx & 31) * 2) = d[j];
            }
            lds_fence();               // data in LDS before the doorbell
            if (l == 0)
                __hip_atomic_store(&sf[wave], (u32)s, __ATOMIC_RELAXED,
                                   __HIP_MEMORY_SCOPE_WORKGROUP);
        }

        // ---- xp prefetch for s+1 (LDS spins below don't touch vmcnt) ----
        if (s + 1 < T_STEPS) xpw_n = xp[((size_t)(s + 1) * 64 + cw) * 64 + l];

        // ---- COMPUTE: consume slices 0..7 with doorbell spins + 1-ahead check ----
        floatx4 acc0, acc1;
        acc0[0] = bf2f((u32)(xpw      ) & 0xFFFFu);
        acc0[1] = bf2f((u32)(xpw >> 16) & 0xFFFFu);
        acc0[2] = bf2f((u32)(xpw >> 32) & 0xFFFFu);
        acc0[3] = bf2f((u32)(xpw >> 48) & 0xFFFFu);
        acc1[0] = 0.f; acc1[1] = 0.f; acc1[2] = 0.f; acc1[3] = 0.f;

        u32 fn = __hip_atomic_load(&sf[0], __ATOMIC_RELAXED, __HIP_MEMORY_SCOPE_WORKGROUP);
        #pragma unroll
        for (int sl = 0; sl < 8; ++sl) {
            if (fn < (u32)s) {
                int r = 0;
                while (!s_dead_v) {
                    fn = __hip_atomic_load(&sf[sl], __ATOMIC_RELAXED,
                                           __HIP_MEMORY_SCOPE_WORKGROUP);
                    if (fn >= (u32)s) break;
                    if (++r > (1 << 20)) { s_dead_v = 1; break; }
                }
            }
            asm volatile("" ::: "memory");                // no A-read hoisting past check
            __builtin_amdgcn_sched_barrier(0);
            if (sl < 7)                                    // flag prefetch overlaps MFMAs
                fn = __hip_atomic_load(&sf[sl + 1], __ATOMIC_RELAXED,
                                       __HIP_MEMORY_SCOPE_WORKGROUP);
            #pragma unroll
            for (int t = 2 * sl; t <= 2 * sl + 1; ++t) {
                uint4 a0 = *(const uint4*)&lds[c * LDS_ROW + (2 * t    ) * 16 + quad * 4];
                uint4 a1 = *(const uint4*)&lds[c * LDS_ROW + (2 * t + 1) * 16 + quad * 4];
                acc0 = __builtin_amdgcn_mfma_f32_16x16x32_bf16(
                           __builtin_bit_cast(short8, a0), wf[2 * t    ], acc0, 0, 0, 0);
                acc1 = __builtin_amdgcn_mfma_f32_16x16x32_bf16(
                           __builtin_bit_cast(short8, a1), wf[2 * t + 1], acc1, 0, 0, 0);
            }
        }

        #pragma unroll
        for (int i = 0; i < 4; ++i) h[i] = tanh_fast(acc0[i] + acc1[i]);

        // force xp prefetch completion HERE so the fence waits only on publishes
        asm volatile("" :: "v"(xpw_n));

        // ---- publish h(s+1) -> parity (s+1)&1; per-wave fence; per-wave flag ----
        u32* bufw = hbuf + (size_t)((s + 1) & 1) * (16 * 512);
        #pragma unroll
        for (int i = 0; i < 4; ++i) {
            int bt = quad * 4 + i;
            float o = __shfl_xor(h[i], 1);
            if (!(c & 1) && bt < 15) {
                u32 data = f2bf1(h[i]) | (f2bf1(o) << 16);
                pub_store32(bufw + bt * 512 + (col >> 1), data);
            }
        }
        release_fence();
        if (l == 0) pub_store64(fl + (size_t)wgf * 8, (u64)(s + 1));

        if (s_dead_v) break;
    }

    // ---------------- epilogue: elected WG 0 computes the sigmoid head ----------------
    if (g == 0) {
        if (!s_dead_v) {
            // wave w stages slice w of parity 0 (h(T)), flags >= T
            const u64 want = (u64)T_STEPS;
            int r = 0;
            while (true) {
                u64 f = mb_load(fl + (size_t)(wave * 8 + (l & 7)) * 8);
                if (__all((int)(f >= want))) break;
                if (++r > (1 << 18)) break;
            }
            u32* lds = &h_lds[0][0];
            const u64* srcp = (const u64*)(hbuf);          // parity 0
            u64 d[8];
            #pragma unroll
            for (int j = 0; j < 8; ++j) {
                int idx = l + j * 64;
                if (idx < 480)
                    d[j] = mb_load(srcp + (size_t)(idx >> 5) * 256 + wave * 32 + (idx & 31));
            }
            #pragma unroll
            for (int j = 0; j < 8; ++j) {
                int idx = l + j * 64;
                if (idx < 480)
                    *(u64*)(lds + (size_t)(idx >> 5) * LDS_ROW + wave * 64 + (idx & 31) * 2) = d[j];
            }
        }
        __syncthreads();
        u32* lds = &h_lds[0][0];
        if (tid < 240) {
            int b = tid >> 4, seg = tid & 15;
            float sum = 0.f;
            for (int j = 0; j < 64; ++j) {
                int k = seg * 64 + j;
                u32 pr = lds[b * LDS_ROW + (k >> 1)];
                float hv = bf2f((pr >> ((k & 1) * 16)) & 0xFFFFu);
                sum += hv * W_fc[k];
            }
            red[tid] = sum;
        }
        __syncthreads();
        if (tid < 15) {
            float z = 0.f;
            #pragma unroll
            for (int j = 0; j < 16; ++j) z += red[tid * 16 + j];
            z += b_fc[0];
            out[tid] = 1.0f / (1.0f + __expf(-z));
        }
    }
}

extern "C" void kernel_launch(void* const* d_in, const int* in_sizes, int n_in,
                              void* d_out, int out_size, void* d_ws, size_t ws_size,
                              hipStream_t stream) {
    const float* x    = (const float*)d_in[0];
    const float* W_ih = (const float*)d_in[1];
    const float* b_ih = (const float*)d_in[2];
    const float* W_hh = (const float*)d_in[3];
    const float* b_hh = (const float*)d_in[4];
    const float* W_fc = (const float*)d_in[5];
    const float* b_fc = (const float*)d_in[6];
    float* out = (float*)d_out;

    char* ws    = (char*)d_ws;
    u64*  xp    = (u64*)(ws + OFF_XP);
    u32*  wihb  = (u32*)(ws + OFF_WIHB);
    u32*  hbuf  = (u32*)(ws + OFF_HBUF);
    u64*  fl    = (u64*)(ws + OFF_FLAGS);
    u32*  claim = (u32*)(ws + OFF_CLAIM);

    k_cvt_wih<<<dim3(N_H), dim3(256), 0, stream>>>(W_ih, wihb, claim, hbuf, fl);
    k_xproj<<<dim3(T_STEPS, 4), dim3(256), 0, stream>>>(x, wihb, b_ih, b_hh, xp);
    k_scan<<<dim3(G_LAUNCH), dim3(THREADS), 0, stream>>>(W_hh, xp, hbuf, fl, claim, W_fc, b_fc, out);
}